// Round 1
// baseline (439.263 us; speedup 1.0000x reference)
//
#include <hip/hip_runtime.h>
#include <stdint.h>

// Problem constants (B=4, S=2048, D=4096)
#define DDIM 4096
#define MTOK 8192

typedef __attribute__((ext_vector_type(4))) int i32x4;

__device__ __forceinline__ void async16(const void* g, void* l) {
    __builtin_amdgcn_global_load_lds(
        (const __attribute__((address_space(1))) unsigned int*)g,
        (__attribute__((address_space(3))) unsigned int*)l,
        16, 0, 0);
}

// ---------------- Quantization kernels ----------------
// One block (256 threads) per row of length 4096.
// MODE 0: t = x*scales (activation); MODE 1: t = w/scales (weight, also writes bq)
template <int MODE>
__global__ __launch_bounds__(256) void quant_rows(
    const float* __restrict__ src, const float* __restrict__ scales,
    signed char* __restrict__ q, float* __restrict__ srow,
    const float* __restrict__ bias, float* __restrict__ bq)
{
    __shared__ float red[4];
    const int row = blockIdx.x;
    const int tid = threadIdx.x;
    const float4* s4 = (const float4*)scales;
    const float4* x4 = (const float4*)(src + (size_t)row * DDIM);

    float4 v[4];
    float am = 0.0f;
#pragma unroll
    for (int j = 0; j < 4; ++j) {
        float4 a = x4[tid + j * 256];
        float4 s = s4[tid + j * 256];
        float4 r;
        if (MODE == 0) { r.x = a.x * s.x; r.y = a.y * s.y; r.z = a.z * s.z; r.w = a.w * s.w; }
        else           { r.x = a.x / s.x; r.y = a.y / s.y; r.z = a.z / s.z; r.w = a.w / s.w; }
        v[j] = r;
        am = fmaxf(am, fmaxf(fmaxf(fabsf(r.x), fabsf(r.y)),
                             fmaxf(fabsf(r.z), fabsf(r.w))));
    }
    // wave64 reduce then cross-wave via LDS
#pragma unroll
    for (int off = 32; off > 0; off >>= 1)
        am = fmaxf(am, __shfl_xor(am, off, 64));
    if ((tid & 63) == 0) red[tid >> 6] = am;
    __syncthreads();
    am = fmaxf(fmaxf(red[0], red[1]), fmaxf(red[2], red[3]));
    am = fmaxf(am, 1e-8f);

    const float sc = 127.0f / am;
    uint32_t* qrow = (uint32_t*)(q + (size_t)row * DDIM);
#pragma unroll
    for (int j = 0; j < 4; ++j) {
        int q0 = (int)fminf(127.0f, fmaxf(-127.0f, rintf(v[j].x * sc)));
        int q1 = (int)fminf(127.0f, fmaxf(-127.0f, rintf(v[j].y * sc)));
        int q2 = (int)fminf(127.0f, fmaxf(-127.0f, rintf(v[j].z * sc)));
        int q3 = (int)fminf(127.0f, fmaxf(-127.0f, rintf(v[j].w * sc)));
        qrow[tid + j * 256] = (uint32_t)(q0 & 0xff) | ((uint32_t)(q1 & 0xff) << 8) |
                              ((uint32_t)(q2 & 0xff) << 16) | ((uint32_t)(q3 & 0xff) << 24);
    }
    if (tid == 0) {
        srow[row] = am * (1.0f / 127.0f);
        if (MODE == 1) bq[row] = bias[row] / scales[row];
    }
}

// ---------------- int8 GEMM: out[m,n] = (sum_k qx[m,k]*qw[n,k]) * sx[m]*sw[n] + bq[n]
// 128x128 tile, BK=64, 256 threads = 4 waves in 2x2, each wave 4x4 of 16x16 MFMA tiles.
__global__ __launch_bounds__(256) void gemm_i8(
    const signed char* __restrict__ qx, const signed char* __restrict__ qw,
    const float* __restrict__ sx, const float* __restrict__ sw,
    const float* __restrict__ bq, float* __restrict__ out)
{
    __shared__ __align__(16) signed char sA[128 * 64];
    __shared__ __align__(16) signed char sB[128 * 64];

    const int K = DDIM, N = DDIM;
    const int tid  = threadIdx.x;
    const int bm   = blockIdx.y;
    const int bn   = blockIdx.x;
    const int wave = tid >> 6;
    const int lane = tid & 63;
    const int wm   = (wave & 1) << 6;   // wave M offset within 128 tile
    const int wn   = (wave >> 1) << 6;  // wave N offset
    const int l16  = lane & 15;
    const int quad = lane >> 4;

    const signed char* Ab = qx + (size_t)bm * 128 * K;
    const signed char* Bb = qw + (size_t)bn * 128 * K;

    // staging chunk indices: thread covers bytes [tid*16, tid*16+16) and +4096
    const int l0 = tid * 16;
    const int r0 = l0 >> 6, c0 = l0 & 63;
    const int l1 = l0 + 4096;
    const int r1 = l1 >> 6, c1 = l1 & 63;

    i32x4 acc[4][4] = {};

    for (int k0 = 0; k0 < K; k0 += 64) {
        async16(Ab + (size_t)r0 * K + k0 + c0, &sA[l0]);
        async16(Ab + (size_t)r1 * K + k0 + c1, &sA[l1]);
        async16(Bb + (size_t)r0 * K + k0 + c0, &sB[l0]);
        async16(Bb + (size_t)r1 * K + k0 + c1, &sB[l1]);
        __syncthreads();

        i32x4 a[4], b[4];
#pragma unroll
        for (int i = 0; i < 4; ++i)
            a[i] = *(const i32x4*)&sA[(wm + i * 16 + l16) * 64 + quad * 16];
#pragma unroll
        for (int j = 0; j < 4; ++j)
            b[j] = *(const i32x4*)&sB[(wn + j * 16 + l16) * 64 + quad * 16];

#pragma unroll
        for (int i = 0; i < 4; ++i)
#pragma unroll
            for (int j = 0; j < 4; ++j)
                acc[i][j] = __builtin_amdgcn_mfma_i32_16x16x64_i8(a[i], b[j], acc[i][j], 0, 0, 0);

        __syncthreads();
    }

    // Epilogue: C/D layout col=lane&15 (n), row=quad*4+reg (m)
#pragma unroll
    for (int i = 0; i < 4; ++i) {
#pragma unroll
        for (int j = 0; j < 4; ++j) {
            const int n = bn * 128 + wn + j * 16 + l16;
            const float swn = sw[n];
            const float bqn = bq[n];
#pragma unroll
            for (int r = 0; r < 4; ++r) {
                const int m = bm * 128 + wm + i * 16 + quad * 4 + r;
                out[(size_t)m * N + n] = (float)acc[i][j][r] * sx[m] * swn + bqn;
            }
        }
    }
}

extern "C" void kernel_launch(void* const* d_in, const int* in_sizes, int n_in,
                              void* d_out, int out_size, void* d_ws, size_t ws_size,
                              hipStream_t stream) {
    const float* x      = (const float*)d_in[0];  // [4,2048,4096]
    const float* weight = (const float*)d_in[1];  // [4096,4096]
    const float* bias   = (const float*)d_in[2];  // [4096]
    const float* scales = (const float*)d_in[3];  // [4096]
    float* out = (float*)d_out;                   // [4,2048,4096]

    char* ws = (char*)d_ws;
    signed char* qx = (signed char*)ws;                       // 8192*4096 = 33554432 B
    signed char* qw = (signed char*)(ws + 33554432);          // 4096*4096 = 16777216 B
    float* sx = (float*)(ws + 50331648);                      // 8192*4 B
    float* sw = (float*)(ws + 50364416);                      // 4096*4 B
    float* bq = (float*)(ws + 50380800);                      // 4096*4 B

    quant_rows<0><<<MTOK, 256, 0, stream>>>(x, scales, qx, sx, nullptr, nullptr);
    quant_rows<1><<<DDIM, 256, 0, stream>>>(weight, scales, qw, sw, bias, bq);

    dim3 grid(DDIM / 128, MTOK / 128);  // (32, 64) = 2048 blocks
    gemm_i8<<<grid, 256, 0, stream>>>(qx, qw, sx, sw, bq, out);
}

// Round 2
// 431.615 us; speedup vs baseline: 1.0177x; 1.0177x over previous
//
#include <hip/hip_runtime.h>
#include <stdint.h>

// Problem constants (B=4, S=2048, D=4096)
#define DDIM 4096
#define MTOK 8192

typedef __attribute__((ext_vector_type(4))) int i32x4;

__device__ __forceinline__ void async16(const void* g, void* l) {
    __builtin_amdgcn_global_load_lds(
        (const __attribute__((address_space(1))) unsigned int*)g,
        (__attribute__((address_space(3))) unsigned int*)l,
        16, 0, 0);
}

// ---------------- Fused quantization kernel ----------------
// Blocks [0, MTOK): activation rows, t = x*scales
// Blocks [MTOK, MTOK+DDIM): weight rows, t = w/scales (also writes bq)
__global__ __launch_bounds__(256) void quant_all(
    const float* __restrict__ x, const float* __restrict__ weight,
    const float* __restrict__ scales,
    signed char* __restrict__ qx, float* __restrict__ sx,
    signed char* __restrict__ qw, float* __restrict__ sw,
    const float* __restrict__ bias, float* __restrict__ bq)
{
    __shared__ float red[4];
    const int tid = threadIdx.x;
    const bool is_x = blockIdx.x < MTOK;
    const int row = is_x ? blockIdx.x : (blockIdx.x - MTOK);
    const float* src = is_x ? (x + (size_t)row * DDIM) : (weight + (size_t)row * DDIM);
    signed char* q = is_x ? qx : qw;
    float* srow = is_x ? sx : sw;

    const float4* s4 = (const float4*)scales;
    const float4* x4 = (const float4*)src;

    float4 v[4];
    float am = 0.0f;
#pragma unroll
    for (int j = 0; j < 4; ++j) {
        float4 a = x4[tid + j * 256];
        float4 s = s4[tid + j * 256];
        float4 r;
        if (is_x) { r.x = a.x * s.x; r.y = a.y * s.y; r.z = a.z * s.z; r.w = a.w * s.w; }
        else      { r.x = a.x / s.x; r.y = a.y / s.y; r.z = a.z / s.z; r.w = a.w / s.w; }
        v[j] = r;
        am = fmaxf(am, fmaxf(fmaxf(fabsf(r.x), fabsf(r.y)),
                             fmaxf(fabsf(r.z), fabsf(r.w))));
    }
#pragma unroll
    for (int off = 32; off > 0; off >>= 1)
        am = fmaxf(am, __shfl_xor(am, off, 64));
    if ((tid & 63) == 0) red[tid >> 6] = am;
    __syncthreads();
    am = fmaxf(fmaxf(red[0], red[1]), fmaxf(red[2], red[3]));
    am = fmaxf(am, 1e-8f);

    const float sc = 127.0f / am;
    uint32_t* qrow = (uint32_t*)(q + (size_t)row * DDIM);
#pragma unroll
    for (int j = 0; j < 4; ++j) {
        int q0 = (int)fminf(127.0f, fmaxf(-127.0f, rintf(v[j].x * sc)));
        int q1 = (int)fminf(127.0f, fmaxf(-127.0f, rintf(v[j].y * sc)));
        int q2 = (int)fminf(127.0f, fmaxf(-127.0f, rintf(v[j].z * sc)));
        int q3 = (int)fminf(127.0f, fmaxf(-127.0f, rintf(v[j].w * sc)));
        qrow[tid + j * 256] = (uint32_t)(q0 & 0xff) | ((uint32_t)(q1 & 0xff) << 8) |
                              ((uint32_t)(q2 & 0xff) << 16) | ((uint32_t)(q3 & 0xff) << 24);
    }
    if (tid == 0) {
        srow[row] = am * (1.0f / 127.0f);
        if (!is_x) bq[row] = bias[row] / scales[row];
    }
}

// ---------------- int8 GEMM: out[m,n] = (sum_k qx[m,k]*qw[n,k]) * sx[m]*sw[n] + bq[n]
// 128x128 tile, BK=64, 256 threads = 4 waves in 2x2, each wave 4x4 of 16x16 MFMA tiles.
// LDS layout XOR-swizzled: 16B chunk of (row, kc) stored at chunk c = kc ^ ((row>>1)&3).
// Swizzle applied on the GLOBAL fetch address (global_load_lds dst is fixed base+lane*16).
__global__ __launch_bounds__(256) void gemm_i8(
    const signed char* __restrict__ qx, const signed char* __restrict__ qw,
    const float* __restrict__ sx, const float* __restrict__ sw,
    const float* __restrict__ bq, float* __restrict__ out)
{
    __shared__ __align__(16) signed char sA[128 * 64];
    __shared__ __align__(16) signed char sB[128 * 64];

    const int K = DDIM, N = DDIM;
    const int tid  = threadIdx.x;
    const int bm   = blockIdx.y;
    const int bn   = blockIdx.x;
    const int wave = tid >> 6;
    const int lane = tid & 63;
    const int wm   = (wave & 1) << 6;   // wave M offset within 128 tile
    const int wn   = (wave >> 1) << 6;  // wave N offset
    const int l16  = lane & 15;
    const int quad = lane >> 4;

    const signed char* Ab = qx + (size_t)bm * 128 * K;
    const signed char* Bb = qw + (size_t)bn * 128 * K;

    // staging: thread fills LDS bytes [tid*16,+16) and [tid*16+4096,+16)
    // LDS position p -> row=p>>6, c=(p>>4)&3; fetch global k-chunk kc = c ^ ((row>>1)&3)
    const int l0 = tid * 16;
    const int r0 = l0 >> 6;
    const int g0 = ((((l0 >> 4) & 3) ^ ((r0 >> 1) & 3)) << 4);
    const int l1 = l0 + 4096;
    const int r1 = l1 >> 6;
    const int g1 = ((((l1 >> 4) & 3) ^ ((r1 >> 1) & 3)) << 4);

    // reader swizzle: chunk = quad ^ ((row>>1)&3); row ≡ l16 (mod 16 offsets don't affect bits 1..2? they do not: wm+i*16 is mult of 16)
    const int rchunk = ((quad ^ ((l16 >> 1) & 3)) << 4);

    i32x4 acc[4][4] = {};

    for (int k0 = 0; k0 < K; k0 += 64) {
        async16(Ab + (size_t)r0 * K + k0 + g0, &sA[l0]);
        async16(Ab + (size_t)r1 * K + k0 + g1, &sA[l1]);
        async16(Bb + (size_t)r0 * K + k0 + g0, &sB[l0]);
        async16(Bb + (size_t)r1 * K + k0 + g1, &sB[l1]);
        __syncthreads();

        i32x4 a[4], b[4];
#pragma unroll
        for (int i = 0; i < 4; ++i)
            a[i] = *(const i32x4*)&sA[(wm + i * 16 + l16) * 64 + rchunk];
#pragma unroll
        for (int j = 0; j < 4; ++j)
            b[j] = *(const i32x4*)&sB[(wn + j * 16 + l16) * 64 + rchunk];

#pragma unroll
        for (int i = 0; i < 4; ++i)
#pragma unroll
            for (int j = 0; j < 4; ++j)
                acc[i][j] = __builtin_amdgcn_mfma_i32_16x16x64_i8(a[i], b[j], acc[i][j], 0, 0, 0);

        __syncthreads();
    }

    // Epilogue: C/D layout col=lane&15 (n), row=quad*4+reg (m)
#pragma unroll
    for (int i = 0; i < 4; ++i) {
#pragma unroll
        for (int j = 0; j < 4; ++j) {
            const int n = bn * 128 + wn + j * 16 + l16;
            const float swn = sw[n];
            const float bqn = bq[n];
#pragma unroll
            for (int r = 0; r < 4; ++r) {
                const int m = bm * 128 + wm + i * 16 + quad * 4 + r;
                out[(size_t)m * N + n] = (float)acc[i][j][r] * sx[m] * swn + bqn;
            }
        }
    }
}

extern "C" void kernel_launch(void* const* d_in, const int* in_sizes, int n_in,
                              void* d_out, int out_size, void* d_ws, size_t ws_size,
                              hipStream_t stream) {
    const float* x      = (const float*)d_in[0];  // [4,2048,4096]
    const float* weight = (const float*)d_in[1];  // [4096,4096]
    const float* bias   = (const float*)d_in[2];  // [4096]
    const float* scales = (const float*)d_in[3];  // [4096]
    float* out = (float*)d_out;                   // [4,2048,4096]

    char* ws = (char*)d_ws;
    signed char* qx = (signed char*)ws;                       // 8192*4096 = 33554432 B
    signed char* qw = (signed char*)(ws + 33554432);          // 4096*4096 = 16777216 B
    float* sx = (float*)(ws + 50331648);                      // 8192*4 B
    float* sw = (float*)(ws + 50364416);                      // 4096*4 B
    float* bq = (float*)(ws + 50380800);                      // 4096*4 B

    quant_all<<<MTOK + DDIM, 256, 0, stream>>>(x, weight, scales, qx, sx, qw, sw, bias, bq);

    dim3 grid(DDIM / 128, MTOK / 128);  // (32, 64) = 2048 blocks
    gemm_i8<<<grid, 256, 0, stream>>>(qx, qw, sx, sw, bq, out);
}

// Round 3
// 417.354 us; speedup vs baseline: 1.0525x; 1.0342x over previous
//
#include <hip/hip_runtime.h>
#include <stdint.h>

// Problem constants (B=4, S=2048, D=4096)
#define DDIM 4096
#define MTOK 8192

typedef __attribute__((ext_vector_type(4))) int i32x4;
typedef __attribute__((ext_vector_type(16))) int i32x16;

__device__ __forceinline__ void async16(const void* g, void* l) {
    __builtin_amdgcn_global_load_lds(
        (const __attribute__((address_space(1))) unsigned int*)g,
        (__attribute__((address_space(3))) unsigned int*)l,
        16, 0, 0);
}

// ---------------- Fused quantization kernel ----------------
// Blocks [0, MTOK): activation rows, t = x*scales
// Blocks [MTOK, MTOK+DDIM): weight rows, t = w/scales (also writes bq)
__global__ __launch_bounds__(256) void quant_all(
    const float* __restrict__ x, const float* __restrict__ weight,
    const float* __restrict__ scales,
    signed char* __restrict__ qx, float* __restrict__ sx,
    signed char* __restrict__ qw, float* __restrict__ sw,
    const float* __restrict__ bias, float* __restrict__ bq)
{
    __shared__ float red[4];
    const int tid = threadIdx.x;
    const bool is_x = blockIdx.x < MTOK;
    const int row = is_x ? blockIdx.x : (blockIdx.x - MTOK);
    const float* src = is_x ? (x + (size_t)row * DDIM) : (weight + (size_t)row * DDIM);
    signed char* q = is_x ? qx : qw;
    float* srow = is_x ? sx : sw;

    const float4* s4 = (const float4*)scales;
    const float4* x4 = (const float4*)src;

    float4 v[4];
    float am = 0.0f;
#pragma unroll
    for (int j = 0; j < 4; ++j) {
        float4 a = x4[tid + j * 256];
        float4 s = s4[tid + j * 256];
        float4 r;
        if (is_x) { r.x = a.x * s.x; r.y = a.y * s.y; r.z = a.z * s.z; r.w = a.w * s.w; }
        else      { r.x = a.x / s.x; r.y = a.y / s.y; r.z = a.z / s.z; r.w = a.w / s.w; }
        v[j] = r;
        am = fmaxf(am, fmaxf(fmaxf(fabsf(r.x), fabsf(r.y)),
                             fmaxf(fabsf(r.z), fabsf(r.w))));
    }
#pragma unroll
    for (int off = 32; off > 0; off >>= 1)
        am = fmaxf(am, __shfl_xor(am, off, 64));
    if ((tid & 63) == 0) red[tid >> 6] = am;
    __syncthreads();
    am = fmaxf(fmaxf(red[0], red[1]), fmaxf(red[2], red[3]));
    am = fmaxf(am, 1e-8f);

    const float sc = 127.0f / am;
    uint32_t* qrow = (uint32_t*)(q + (size_t)row * DDIM);
#pragma unroll
    for (int j = 0; j < 4; ++j) {
        int q0 = (int)fminf(127.0f, fmaxf(-127.0f, rintf(v[j].x * sc)));
        int q1 = (int)fminf(127.0f, fmaxf(-127.0f, rintf(v[j].y * sc)));
        int q2 = (int)fminf(127.0f, fmaxf(-127.0f, rintf(v[j].z * sc)));
        int q3 = (int)fminf(127.0f, fmaxf(-127.0f, rintf(v[j].w * sc)));
        qrow[tid + j * 256] = (uint32_t)(q0 & 0xff) | ((uint32_t)(q1 & 0xff) << 8) |
                              ((uint32_t)(q2 & 0xff) << 16) | ((uint32_t)(q3 & 0xff) << 24);
    }
    if (tid == 0) {
        srow[row] = am * (1.0f / 127.0f);
        if (!is_x) bq[row] = bias[row] / scales[row];
    }
}

// ---------------- int8 GEMM: out[m,n] = (sum_k qx[m,k]*qw[n,k]) * sx[m]*sw[n] + bq[n]
// 128x128 block tile, BK=128 (32 KB LDS), 256 threads = 4 waves in 2x2.
// Wave tile 64x64 = 2x2 of 32x32x32 i8 MFMAs (4404 TOPS ceiling, 16 regs acc each).
// LDS rows are 128 B (= 32 banks); 16 B chunk kc of row r stored at chunk kc ^ (r&7)
// so 32-consecutive-row fragment reads spread 8 lanes per 4-bank group (conflict-free).
// Swizzle applied on the GLOBAL fetch address (global_load_lds dst is fixed base+lane*16).
// Correctness invariant: A and B use the identical k-chunk permutation, so the MFMA
// contraction is unchanged.
__global__ __launch_bounds__(256) void gemm_i8(
    const signed char* __restrict__ qx, const signed char* __restrict__ qw,
    const float* __restrict__ sx, const float* __restrict__ sw,
    const float* __restrict__ bq, float* __restrict__ out)
{
    __shared__ __align__(16) signed char sA[128 * 128];
    __shared__ __align__(16) signed char sB[128 * 128];

    const int K = DDIM, N = DDIM;
    const int tid  = threadIdx.x;
    const int bm   = blockIdx.y;
    const int bn   = blockIdx.x;
    const int wave = tid >> 6;
    const int lane = tid & 63;
    const int wm   = (wave & 1) << 6;   // wave M offset within 128 tile
    const int wn   = (wave >> 1) << 6;  // wave N offset
    const int r5   = lane & 31;         // fragment row within 32-row tile
    const int hi   = lane >> 5;         // k-half selector

    const signed char* Ab = qx + (size_t)bm * 128 * K;
    const signed char* Bb = qw + (size_t)bn * 128 * K;

    // Staging: thread covers LDS bytes p = tid*16 + c*4096, c in 0..3 (per matrix).
    // p -> row = p>>7 = (tid>>3) + 32c ; chunk-in-row cir = tid&7.
    // Fetch global k-chunk kc = cir ^ (row & 7).
    const int srow0 = tid >> 3;
    const int cir   = tid & 7;

    // Reader chunk offsets: for k-quarter kq, k-chunk = kq*2 + hi, stored at
    // (kq*2+hi) ^ (r5&7); byte offset within row = that * 16.
    int roff[4];
#pragma unroll
    for (int kq = 0; kq < 4; ++kq)
        roff[kq] = (((kq * 2 + hi) ^ (r5 & 7)) << 4);

    i32x16 acc[2][2] = {};

    for (int k0 = 0; k0 < K; k0 += 128) {
#pragma unroll
        for (int c = 0; c < 4; ++c) {
            const int row = srow0 + 32 * c;
            const int kc  = cir ^ (row & 7);
            const int p   = tid * 16 + c * 4096;
            async16(Ab + (size_t)row * K + k0 + kc * 16, &sA[p]);
            async16(Bb + (size_t)row * K + k0 + kc * 16, &sB[p]);
        }
        __syncthreads();

#pragma unroll
        for (int kq = 0; kq < 4; ++kq) {
            i32x4 a0 = *(const i32x4*)&sA[(wm +      r5) * 128 + roff[kq]];
            i32x4 a1 = *(const i32x4*)&sA[(wm + 32 + r5) * 128 + roff[kq]];
            i32x4 b0 = *(const i32x4*)&sB[(wn +      r5) * 128 + roff[kq]];
            i32x4 b1 = *(const i32x4*)&sB[(wn + 32 + r5) * 128 + roff[kq]];
            acc[0][0] = __builtin_amdgcn_mfma_i32_32x32x32_i8(a0, b0, acc[0][0], 0, 0, 0);
            acc[0][1] = __builtin_amdgcn_mfma_i32_32x32x32_i8(a0, b1, acc[0][1], 0, 0, 0);
            acc[1][0] = __builtin_amdgcn_mfma_i32_32x32x32_i8(a1, b0, acc[1][0], 0, 0, 0);
            acc[1][1] = __builtin_amdgcn_mfma_i32_32x32x32_i8(a1, b1, acc[1][1], 0, 0, 0);
        }

        __syncthreads();
    }

    // Epilogue: 32x32 C/D layout col(n) = lane&31, row(m) = (reg&3) + 8*(reg>>2) + 4*hi
#pragma unroll
    for (int mi = 0; mi < 2; ++mi) {
#pragma unroll
        for (int nj = 0; nj < 2; ++nj) {
            const int n = bn * 128 + wn + nj * 32 + r5;
            const float swn = sw[n];
            const float bqn = bq[n];
            const int mbase = bm * 128 + wm + mi * 32 + 4 * hi;
#pragma unroll
            for (int r = 0; r < 16; ++r) {
                const int m = mbase + (r & 3) + 8 * (r >> 2);
                out[(size_t)m * N + n] = (float)acc[mi][nj][r] * sx[m] * swn + bqn;
            }
        }
    }
}

extern "C" void kernel_launch(void* const* d_in, const int* in_sizes, int n_in,
                              void* d_out, int out_size, void* d_ws, size_t ws_size,
                              hipStream_t stream) {
    const float* x      = (const float*)d_in[0];  // [4,2048,4096]
    const float* weight = (const float*)d_in[1];  // [4096,4096]
    const float* bias   = (const float*)d_in[2];  // [4096]
    const float* scales = (const float*)d_in[3];  // [4096]
    float* out = (float*)d_out;                   // [4,2048,4096]

    char* ws = (char*)d_ws;
    signed char* qx = (signed char*)ws;                       // 8192*4096 = 33554432 B
    signed char* qw = (signed char*)(ws + 33554432);          // 4096*4096 = 16777216 B
    float* sx = (float*)(ws + 50331648);                      // 8192*4 B
    float* sw = (float*)(ws + 50364416);                      // 4096*4 B
    float* bq = (float*)(ws + 50380800);                      // 4096*4 B

    quant_all<<<MTOK + DDIM, 256, 0, stream>>>(x, weight, scales, qx, sx, qw, sw, bias, bq);

    dim3 grid(DDIM / 128, MTOK / 128);  // (32, 64) = 2048 blocks
    gemm_i8<<<grid, 256, 0, stream>>>(qx, qw, sx, sw, bq, out);
}